// Round 3
// baseline (816.438 us; speedup 1.0000x reference)
//
#include <hip/hip_runtime.h>

#define G_DATA 262144
#define G_TRUNC 40000
#define E_EDGES 1048576
#define FEAT 128
#define EPS 1e-8f

// ======================= CSR-gather path =================================

// counts[dst[e]] += 1
__global__ __launch_bounds__(256) void hist_kernel(const int* __restrict__ dst,
                                                   int* __restrict__ counts) {
    int e = blockIdx.x * 256 + threadIdx.x;
    if (e < E_EDGES) atomicAdd(&counts[dst[e]], 1);
}

// per-block exclusive scan (block size 1024), block totals to bsums
__global__ __launch_bounds__(1024) void scan_block(const int* __restrict__ counts,
                                                   int rows,
                                                   int* __restrict__ off,
                                                   int* __restrict__ bsums) {
    __shared__ int s[1024];
    int tid = threadIdx.x;
    int idx = blockIdx.x * 1024 + tid;
    int c = (idx < rows) ? counts[idx] : 0;
    s[tid] = c;
    for (int d = 1; d < 1024; d <<= 1) {
        __syncthreads();
        int t = (tid >= d) ? s[tid - d] : 0;
        __syncthreads();
        s[tid] += t;
    }
    if (idx < rows) off[idx] = s[tid] - c;          // exclusive within block
    if (tid == 1023) bsums[blockIdx.x] = s[1023];   // block total
}

// exclusive scan of block sums (n <= 256), single block
__global__ __launch_bounds__(256) void scan_bsums(int* __restrict__ bsums, int n) {
    __shared__ int s[256];
    int tid = threadIdx.x;
    int v = (tid < n) ? bsums[tid] : 0;
    s[tid] = v;
    for (int d = 1; d < 256; d <<= 1) {
        __syncthreads();
        int t = (tid >= d) ? s[tid - d] : 0;
        __syncthreads();
        s[tid] += t;
    }
    if (tid < n) bsums[tid] = s[tid] - v;           // exclusive
}

// off[i] += bsums[i>>10]; cursor[i] = off[i]; off[rows] = total
__global__ __launch_bounds__(256) void finalize_off(int* __restrict__ off,
                                                    const int* __restrict__ bsums,
                                                    int* __restrict__ cursor,
                                                    int rows, int total) {
    int idx = blockIdx.x * 256 + threadIdx.x;
    if (idx < rows) {
        int o = off[idx] + bsums[idx >> 10];
        off[idx] = o;
        cursor[idx] = o;
    }
    if (idx == 0) off[rows] = total;
}

// pairs[atomicAdd(cursor[dst[e]])] = (src[e], bits(w[e]))
__global__ __launch_bounds__(256) void scatter_pairs(const int* __restrict__ src,
                                                     const int* __restrict__ dst,
                                                     const float* __restrict__ w,
                                                     int* __restrict__ cursor,
                                                     int2* __restrict__ pairs) {
    int e = blockIdx.x * 256 + threadIdx.x;
    if (e >= E_EDGES) return;
    int d = dst[e];
    int pos = atomicAdd(&cursor[d], 1);
    pairs[pos] = make_int2(src[e], __float_as_int(w[e]));
}

// one wave per row: out[r] = (sum_e w_e * x[src_e]) / max(sum_e w_e, EPS)
__global__ __launch_bounds__(256) void gather_rows(const float* __restrict__ xsrc,
                                                   const int2* __restrict__ pairs,
                                                   const int* __restrict__ off,
                                                   float* __restrict__ out,
                                                   int rows) {
    long gid = (long)blockIdx.x * 256 + threadIdx.x;
    int r    = (int)(gid >> 6);
    int lane = (int)(gid & 63);
    if (r >= rows) return;
    int beg = off[r], end = off[r + 1];
    float ax = 0.f, ay = 0.f, wsum = 0.f;
    for (int k = beg; k < end; ++k) {
        int2 p = pairs[k];                           // wave-uniform 8B broadcast
        float ww = __int_as_float(p.y);
        float2 v = ((const float2*)(xsrc + (size_t)p.x * FEAT))[lane];  // coalesced 512B
        ax += ww * v.x;
        ay += ww * v.y;
        wsum += ww;
    }
    float den = fmaxf(wsum, EPS);
    float2 o;
    o.x = ax / den;
    o.y = ay / den;
    ((float2*)(out + (size_t)r * FEAT))[lane] = o;
}

// ======================= fallback atomic path ============================

__global__ __launch_bounds__(256) void norm_accum(const int* __restrict__ dst,
                                                  const float* __restrict__ w,
                                                  float* __restrict__ norm) {
    int i = blockIdx.x * blockDim.x + threadIdx.x;
    if (i < E_EDGES) atomicAdd(&norm[dst[i]], w[i]);
}

__global__ __launch_bounds__(256) void scatter_accum(const float* __restrict__ xsrc,
                                                     const int* __restrict__ src,
                                                     const int* __restrict__ dst,
                                                     const float* __restrict__ w,
                                                     float* __restrict__ out) {
    long gid = (long)blockIdx.x * blockDim.x + threadIdx.x;
    int e    = (int)(gid >> 6);
    int lane = (int)(gid & 63);
    if (e >= E_EDGES) return;
    int   s  = src[e];
    int   d  = dst[e];
    float ww = w[e];
    float2 v = ((const float2*)(xsrc + (size_t)s * FEAT))[lane];
    float* op = out + (size_t)d * FEAT + lane * 2;
    atomicAdd(op,     v.x * ww);
    atomicAdd(op + 1, v.y * ww);
}

__global__ __launch_bounds__(256) void row_divide(float* __restrict__ data,
                                                  const float* __restrict__ norm,
                                                  int rows) {
    long gid = (long)blockIdx.x * blockDim.x + threadIdx.x;
    int r = (int)(gid >> 5);
    int c = (int)(gid & 31);
    if (r >= rows) return;
    float den = fmaxf(norm[r], EPS);
    float4* p = (float4*)(data + (size_t)r * FEAT) + c;
    float4 v = *p;
    v.x /= den; v.y /= den; v.z /= den; v.w /= den;
    *p = v;
}

// =========================================================================

extern "C" void kernel_launch(void* const* d_in, const int* in_sizes, int n_in,
                              void* d_out, int out_size, void* d_ws, size_t ws_size,
                              hipStream_t stream) {
    const float* x        = (const float*)d_in[0];
    const int*   down_src = (const int*)  d_in[1];
    const int*   down_dst = (const int*)  d_in[2];
    const float* down_w   = (const float*)d_in[3];
    const int*   up_src   = (const int*)  d_in[4];
    const int*   up_dst   = (const int*)  d_in[5];
    const float* up_w     = (const float*)d_in[6];
    float*       out      = (float*)d_out;

    // x has shape (1, 2, 1, G_DATA, FEAT); reference takes x[:, -1] -> 2nd slab
    const float* xt = x + (size_t)G_DATA * FEAT;

    // ---- CSR workspace layout (4B units) ----
    // xc[G_TRUNC*FEAT] | off[G_DATA+2] | cursor[G_DATA] | counts[G_DATA] |
    // bsums[256] | pairs[E_EDGES] (int2, 8B-aligned by construction)
    const size_t XC_I    = (size_t)G_TRUNC * FEAT;      // 5,120,000
    const size_t OFF_I   = G_DATA + 2;                  // 262,146 (padded even)
    const size_t CUR_I   = G_DATA;
    const size_t CNT_I   = G_DATA;
    const size_t BS_I    = 256;
    const size_t csr_ints = XC_I + OFF_I + CUR_I + CNT_I + BS_I + (size_t)E_EDGES * 2;
    const size_t csr_need = csr_ints * 4;               // ~32.0 MB

    if (ws_size >= csr_need) {
        float* xc     = (float*)d_ws;
        int*   off    = (int*)(xc + XC_I);
        int*   cursor = off + OFF_I;
        int*   counts = cursor + CUR_I;
        int*   bsums  = counts + CNT_I;
        int2*  pairs  = (int2*)(bsums + BS_I);

        const int* SRC[2] = { down_src, up_src };
        const int* DST[2] = { down_dst, up_dst };
        const float* WW[2] = { down_w, up_w };
        const float* XS[2] = { xt, xc };
        float* OUT[2] = { xc, out };
        const int ROWS[2] = { G_TRUNC, G_DATA };

        for (int ph = 0; ph < 2; ++ph) {
            int rows = ROWS[ph];
            int nblk = (rows + 1023) / 1024;            // 40 or 256
            hipMemsetAsync(counts, 0, (size_t)rows * 4, stream);
            hist_kernel<<<E_EDGES / 256, 256, 0, stream>>>(DST[ph], counts);
            scan_block<<<nblk, 1024, 0, stream>>>(counts, rows, off, bsums);
            scan_bsums<<<1, 256, 0, stream>>>(bsums, nblk);
            finalize_off<<<(rows + 255) / 256, 256, 0, stream>>>(off, bsums, cursor, rows, E_EDGES);
            scatter_pairs<<<E_EDGES / 256, 256, 0, stream>>>(SRC[ph], DST[ph], WW[ph], cursor, pairs);
            gather_rows<<<((long)rows * 64 + 255) / 256, 256, 0, stream>>>(XS[ph], pairs, off, OUT[ph], rows);
        }
    } else {
        // ---- fallback: atomic scatter (needs 21.7 MB) ----
        float* xc        = (float*)d_ws;
        float* norm_down = xc + (size_t)G_TRUNC * FEAT;
        float* norm_up   = norm_down + G_TRUNC;

        size_t ws_need = ((size_t)G_TRUNC * FEAT + G_TRUNC + G_DATA) * sizeof(float);
        size_t ws_zero = ws_need <= ws_size ? ws_need : ws_size;
        hipMemsetAsync(d_ws, 0, ws_zero, stream);
        hipMemsetAsync(d_out, 0, (size_t)out_size * sizeof(float), stream);

        norm_accum<<<E_EDGES / 256, 256, 0, stream>>>(down_dst, down_w, norm_down);
        norm_accum<<<E_EDGES / 256, 256, 0, stream>>>(up_dst,   up_w,   norm_up);
        scatter_accum<<<(E_EDGES * 64) / 256, 256, 0, stream>>>(xt, down_src, down_dst, down_w, xc);
        row_divide<<<(G_TRUNC * 32 + 255) / 256, 256, 0, stream>>>(xc, norm_down, G_TRUNC);
        scatter_accum<<<(E_EDGES * 64) / 256, 256, 0, stream>>>(xc, up_src, up_dst, up_w, out);
        row_divide<<<(G_DATA * 32 + 255) / 256, 256, 0, stream>>>(out, norm_up, G_DATA);
    }
}

// Round 4
// 734.132 us; speedup vs baseline: 1.1121x; 1.1121x over previous
//
#include <hip/hip_runtime.h>

#define G_DATA 262144
#define G_TRUNC 40000
#define E_EDGES 1048576
#define FEAT 128
#define EPS 1e-8f
#define NBUCKET (G_TRUNC + G_DATA)          // combined bucket count: 302144

// counts[down_dst[e]]++ for e<E; counts[G_TRUNC+up_dst[e-E]]++ for e>=E
__global__ __launch_bounds__(256) void hist_fused(const int* __restrict__ down_dst,
                                                  const int* __restrict__ up_dst,
                                                  int* __restrict__ counts) {
    int e = blockIdx.x * 256 + threadIdx.x;
    if (e < E_EDGES)            atomicAdd(&counts[down_dst[e]], 1);
    else                        atomicAdd(&counts[G_TRUNC + up_dst[e - E_EDGES]], 1);
}

// per-block exclusive scan (1024 wide), block totals to bsums
__global__ __launch_bounds__(1024) void scan_block(const int* __restrict__ counts,
                                                   int rows,
                                                   int* __restrict__ off,
                                                   int* __restrict__ bsums) {
    __shared__ int s[1024];
    int tid = threadIdx.x;
    int idx = blockIdx.x * 1024 + tid;
    int c = (idx < rows) ? counts[idx] : 0;
    s[tid] = c;
    for (int d = 1; d < 1024; d <<= 1) {
        __syncthreads();
        int t = (tid >= d) ? s[tid - d] : 0;
        __syncthreads();
        s[tid] += t;
    }
    if (idx < rows) off[idx] = s[tid] - c;
    if (tid == 1023) bsums[blockIdx.x] = s[1023];
}

// exclusive scan of block sums (n <= 512), single block
__global__ __launch_bounds__(512) void scan_bsums(int* __restrict__ bsums, int n) {
    __shared__ int s[512];
    int tid = threadIdx.x;
    int v = (tid < n) ? bsums[tid] : 0;
    s[tid] = v;
    for (int d = 1; d < 512; d <<= 1) {
        __syncthreads();
        int t = (tid >= d) ? s[tid - d] : 0;
        __syncthreads();
        s[tid] += t;
    }
    if (tid < n) bsums[tid] = s[tid] - v;
}

// off[i] += bsums[i>>10]; cursor[i] = off[i]; off[rows] = total
__global__ __launch_bounds__(256) void finalize_off(int* __restrict__ off,
                                                    const int* __restrict__ bsums,
                                                    int* __restrict__ cursor,
                                                    int rows, int total) {
    int idx = blockIdx.x * 256 + threadIdx.x;
    if (idx < rows) {
        int o = off[idx] + bsums[idx >> 10];
        off[idx] = o;
        cursor[idx] = o;
    }
    if (idx == 0) off[rows] = total;
}

// pairs[cursor[bucket]++] = (src, bits(w)) for both edge lists
__global__ __launch_bounds__(256) void scatter_fused(const int* __restrict__ down_src,
                                                     const int* __restrict__ down_dst,
                                                     const float* __restrict__ down_w,
                                                     const int* __restrict__ up_src,
                                                     const int* __restrict__ up_dst,
                                                     const float* __restrict__ up_w,
                                                     int* __restrict__ cursor,
                                                     int2* __restrict__ pairs) {
    int e = blockIdx.x * 256 + threadIdx.x;
    int b, s; float ww;
    if (e < E_EDGES) {
        b = down_dst[e];            s = down_src[e];            ww = down_w[e];
    } else {
        int e2 = e - E_EDGES;
        b = G_TRUNC + up_dst[e2];   s = up_src[e2];             ww = up_w[e2];
    }
    int pos = atomicAdd(&cursor[b], 1);
    pairs[pos] = make_int2(s, __float_as_int(ww));
}

// one wave per row, U-deep software-pipelined edge loop
template<int U>
__global__ __launch_bounds__(256) void gather_rows(const float* __restrict__ xsrc,
                                                   const int2* __restrict__ pairs,
                                                   const int* __restrict__ off,
                                                   float* __restrict__ out,
                                                   int rows, int row_base) {
    long gid = (long)blockIdx.x * 256 + threadIdx.x;
    int r    = (int)(gid >> 6);
    int lane = (int)(gid & 63);
    if (r >= rows) return;
    int beg = __builtin_amdgcn_readfirstlane(off[row_base + r]);
    int end = __builtin_amdgcn_readfirstlane(off[row_base + r + 1]);
    float ax = 0.f, ay = 0.f, wsum = 0.f;
    int k = beg;
    for (; k + U <= end; k += U) {
        int2 p[U];
        #pragma unroll
        for (int u = 0; u < U; ++u) p[u] = pairs[k + u];
        float2 v[U];
        #pragma unroll
        for (int u = 0; u < U; ++u)
            v[u] = ((const float2*)(xsrc + (size_t)p[u].x * FEAT))[lane];
        #pragma unroll
        for (int u = 0; u < U; ++u) {
            float ww = __int_as_float(p[u].y);
            ax += ww * v[u].x;
            ay += ww * v[u].y;
            wsum += ww;
        }
    }
    for (; k < end; ++k) {
        int2 p = pairs[k];
        float ww = __int_as_float(p.y);
        float2 v = ((const float2*)(xsrc + (size_t)p.x * FEAT))[lane];
        ax += ww * v.x;
        ay += ww * v.y;
        wsum += ww;
    }
    float den = fmaxf(wsum, EPS);
    float2 o;
    o.x = ax / den;
    o.y = ay / den;
    ((float2*)(out + (size_t)r * FEAT))[lane] = o;
}

extern "C" void kernel_launch(void* const* d_in, const int* in_sizes, int n_in,
                              void* d_out, int out_size, void* d_ws, size_t ws_size,
                              hipStream_t stream) {
    const float* x        = (const float*)d_in[0];
    const int*   down_src = (const int*)  d_in[1];
    const int*   down_dst = (const int*)  d_in[2];
    const float* down_w   = (const float*)d_in[3];
    const int*   up_src   = (const int*)  d_in[4];
    const int*   up_dst   = (const int*)  d_in[5];
    const float* up_w     = (const float*)d_in[6];
    float*       out      = (float*)d_out;

    // x: (1, 2, 1, G_DATA, FEAT); reference takes x[:, -1] -> 2nd slab
    const float* xt = x + (size_t)G_DATA * FEAT;

    // ws layout (4B units, all even offsets -> pairs 8B-aligned):
    // xc[G_TRUNC*FEAT] | counts[NBUCKET] | off[NBUCKET+2] | cursor[NBUCKET] |
    // bsums[512] | pairs[2*E_EDGES int2]
    const size_t XC_I  = (size_t)G_TRUNC * FEAT;   // 5,120,000
    const size_t CNT_I = NBUCKET;                  // 302,144
    const size_t OFF_I = NBUCKET + 2;              // 302,146
    const size_t CUR_I = NBUCKET;
    const size_t BS_I  = 512;

    float* xc     = (float*)d_ws;
    int*   counts = (int*)(xc + XC_I);
    int*   off    = counts + CNT_I;
    int*   cursor = off + OFF_I;
    int*   bsums  = cursor + CUR_I;
    int2*  pairs  = (int2*)(bsums + BS_I);
    // total ~41 MB; ws_size measured at 1 GiB (harness poison fill) -> fits.

    const int TOTAL_E = 2 * E_EDGES;
    const int nblk = (NBUCKET + 1023) / 1024;      // 296

    hipMemsetAsync(counts, 0, (size_t)NBUCKET * 4, stream);
    hist_fused<<<TOTAL_E / 256, 256, 0, stream>>>(down_dst, up_dst, counts);
    scan_block<<<nblk, 1024, 0, stream>>>(counts, NBUCKET, off, bsums);
    scan_bsums<<<1, 512, 0, stream>>>(bsums, nblk);
    finalize_off<<<(NBUCKET + 255) / 256, 256, 0, stream>>>(off, bsums, cursor, NBUCKET, TOTAL_E);
    scatter_fused<<<TOTAL_E / 256, 256, 0, stream>>>(down_src, down_dst, down_w,
                                                     up_src, up_dst, up_w, cursor, pairs);
    // down: xt -> xc (rows 0..G_TRUNC), avg degree ~26 -> U=8
    gather_rows<8><<<((long)G_TRUNC * 64 + 255) / 256, 256, 0, stream>>>(
        xt, pairs, off, xc, G_TRUNC, 0);
    // up: xc -> out (rows G_TRUNC..), avg degree ~4 -> U=4
    gather_rows<4><<<((long)G_DATA * 64 + 255) / 256, 256, 0, stream>>>(
        xc, pairs, off, out, G_DATA, G_TRUNC);
}